// Round 2
// baseline (568.462 us; speedup 1.0000x reference)
//
#include <hip/hip_runtime.h>
#include <cstdint>

typedef unsigned short u16;
typedef __bf16 bf16x8 __attribute__((ext_vector_type(8)));
typedef float f32x4 __attribute__((ext_vector_type(4)));

#define M_DIM 8192   // B*S = 4*2048
#define N_DIM 4096   // UNITS
#define K_DIM 4096   // D

#define GLOBAL_AS(p) ((const __attribute__((address_space(1))) void*)(p))
#define LDS_AS(p)    ((__attribute__((address_space(3))) void*)(p))

// ---------- fp32 -> bf16 bits, round-to-nearest-even ----------
__device__ __forceinline__ u16 f2bf(float f) {
    union { float f; uint32_t u; } x; x.f = f;
    uint32_t u = x.u;
    uint32_t r = (u + 0x7fffu + ((u >> 16) & 1u)) >> 16;
    return (u16)r;
}

// ---------- prepass 1: x fp32 -> bf16, 8 elems/thread ----------
__global__ __launch_bounds__(256) void cvt_x_kernel(const float* __restrict__ X,
                                                    u16* __restrict__ Xb) {
    int i = blockIdx.x * 256 + threadIdx.x;           // one 8-elem chunk per thread
    const float4* x4 = (const float4*)X;
    float4 a = x4[2 * (size_t)i];
    float4 b = x4[2 * (size_t)i + 1];
    __align__(16) u16 o[8];
    o[0] = f2bf(a.x); o[1] = f2bf(a.y); o[2] = f2bf(a.z); o[3] = f2bf(a.w);
    o[4] = f2bf(b.x); o[5] = f2bf(b.y); o[6] = f2bf(b.z); o[7] = f2bf(b.w);
    ((uint4*)Xb)[i] = *(const uint4*)o;
}

// ---------- prepass 2: W (K,N) int32 -> Wt (N,K) bf16, 64x64 LDS tiles ----------
// NOTE: harness materializes integer inputs as int32 ("integer -> const int*"),
// so W is 4 bytes/element even though the reference is int8-valued.
__global__ __launch_bounds__(256) void cvt_w_kernel(const int* __restrict__ W,
                                                    u16* __restrict__ Wt) {
    __shared__ int tile[64][65];                      // +1 pad: conflict-free transposed read
    const int t  = threadIdx.x;
    const int k0 = blockIdx.y * 64;
    const int n0 = blockIdx.x * 64;
    // read 64x64 int32 (16 KB), coalesced 16B per thread x 4 iters
#pragma unroll
    for (int i = 0; i < 4; i++) {
        int e = t + i * 256;                          // int4-chunk index, 1024 total
        int r = e >> 4;                               // row 0..63
        int c = (e & 15) * 4;                         // col 0..60
        int4 v = *(const int4*)(W + (size_t)(k0 + r) * N_DIM + n0 + c);
        tile[r][c] = v.x; tile[r][c + 1] = v.y; tile[r][c + 2] = v.z; tile[r][c + 3] = v.w;
    }
    __syncthreads();
    {   // write Wt[n][k] bf16: thread t covers n = t>>2, k-span (t&3)*16 .. +16
        int n = t >> 2, ks = (t & 3) * 16;
        __align__(16) u16 o[16];
#pragma unroll
        for (int i = 0; i < 16; i++)
            o[i] = f2bf((float)tile[ks + i][n]);
        u16* dst = Wt + (size_t)(n0 + n) * K_DIM + k0 + ks;
        *(uint4*)(dst)     = *(const uint4*)&o[0];
        *(uint4*)(dst + 8) = *(const uint4*)&o[8];
    }
}

// ---------- main GEMM: C[M,N] = (A[M,K]bf16 . Bt[N,K]bf16) * scale ----------
// m97 structure: 128x128 tile, BK=32, 256 threads (4 waves, 2x2 of 64x64),
// global_load_lds width=16 into unpadded LDS, 16x16x32 bf16 MFMA.
__global__ __launch_bounds__(256) void gemm_bf16_kernel(const u16* __restrict__ A,
                                                        const u16* __restrict__ Bt,
                                                        const float* __restrict__ scale_p,
                                                        float* __restrict__ C) {
    __shared__ u16 As[128 * 32];   // [m][k], unpadded (global_load_lds constraint)
    __shared__ u16 Bs[128 * 32];   // [n][k]

    const int tid  = threadIdx.x;
    const int lane = tid & 63;
    const int wv   = tid >> 6;
    const int m0   = blockIdx.y * 128;
    const int n0   = blockIdx.x * 128;

    const int wm = (wv >> 1) * 64;         // wave's 64x64 sub-tile
    const int wn = (wv & 1) * 64;
    const int fr = lane & 15;              // fragment row (m or n)
    const int fk = (lane >> 4) * 8;        // fragment k offset

    // staging: 512 chunks of 16B per tile; thread t covers chunks t and t+256.
    // chunk c -> row c>>2, k-offset (c&3)*8. LDS dest = wave-uniform base + lane*16B.
    const int c0 = tid, c1 = tid + 256;
    const u16* ga0 = A  + (size_t)(m0 + (c0 >> 2)) * K_DIM + (c0 & 3) * 8;
    const u16* ga1 = A  + (size_t)(m0 + (c1 >> 2)) * K_DIM + (c1 & 3) * 8;
    const u16* gb0 = Bt + (size_t)(n0 + (c0 >> 2)) * K_DIM + (c0 & 3) * 8;
    const u16* gb1 = Bt + (size_t)(n0 + (c1 >> 2)) * K_DIM + (c1 & 3) * 8;
    u16* lA0 = As + wv * 512;          // bytes: wv*1024
    u16* lA1 = As + 2048 + wv * 512;   // bytes: 4096 + wv*1024
    u16* lB0 = Bs + wv * 512;
    u16* lB1 = Bs + 2048 + wv * 512;

    f32x4 acc[4][4] = {};

    for (int k0 = 0; k0 < K_DIM; k0 += 32) {
        __builtin_amdgcn_global_load_lds(GLOBAL_AS(ga0 + k0), LDS_AS(lA0), 16, 0, 0);
        __builtin_amdgcn_global_load_lds(GLOBAL_AS(ga1 + k0), LDS_AS(lA1), 16, 0, 0);
        __builtin_amdgcn_global_load_lds(GLOBAL_AS(gb0 + k0), LDS_AS(lB0), 16, 0, 0);
        __builtin_amdgcn_global_load_lds(GLOBAL_AS(gb1 + k0), LDS_AS(lB1), 16, 0, 0);
        __syncthreads();

        bf16x8 af[4], bfr[4];
#pragma unroll
        for (int i = 0; i < 4; i++)
            af[i] = *(const bf16x8*)(As + (wm + i * 16 + fr) * 32 + fk);
#pragma unroll
        for (int j = 0; j < 4; j++)
            bfr[j] = *(const bf16x8*)(Bs + (wn + j * 16 + fr) * 32 + fk);
#pragma unroll
        for (int i = 0; i < 4; i++)
#pragma unroll
            for (int j = 0; j < 4; j++)
                acc[i][j] = __builtin_amdgcn_mfma_f32_16x16x32_bf16(af[i], bfr[j], acc[i][j], 0, 0, 0);
        __syncthreads();
    }

    // epilogue: D layout col=lane&15, row=(lane>>4)*4+reg
    const float s = *scale_p;
    const int orow = m0 + wm + (lane >> 4) * 4;
    const int ocol = n0 + wn + (lane & 15);
#pragma unroll
    for (int i = 0; i < 4; i++)
#pragma unroll
        for (int j = 0; j < 4; j++) {
            float* cp = C + (size_t)(orow + i * 16) * N_DIM + ocol + j * 16;
#pragma unroll
            for (int r = 0; r < 4; r++)
                cp[(size_t)r * N_DIM] = acc[i][j][r] * s;
        }
}

// ---------- fallback fp32 GEMM (only if ws too small; correctness net) ----------
__global__ __launch_bounds__(256) void fb_gemm_kernel(const float* __restrict__ X,
                                                      const int* __restrict__ W,
                                                      const float* __restrict__ sp,
                                                      float* __restrict__ Y) {
    __shared__ float Xs[16][64];
    __shared__ float Ws[16][64];
    const int t = threadIdx.x;
    const int tx = t & 15, ty = t >> 4;
    const int m0 = blockIdx.y * 64, n0 = blockIdx.x * 64;
    float acc[4][4] = {};
    for (int k0 = 0; k0 < K_DIM; k0 += 16) {
#pragma unroll
        for (int i = 0; i < 4; i++) {
            int e = t + i * 256;
            int r = e >> 4, c = e & 15;                 // 64 rows x 16 k
            Xs[c][r] = X[(size_t)(m0 + r) * K_DIM + k0 + c];
            int rw = e >> 6, cw = e & 63;               // 16 k x 64 n
            Ws[rw][cw] = (float)W[(size_t)(k0 + rw) * N_DIM + n0 + cw];
        }
        __syncthreads();
#pragma unroll
        for (int kk = 0; kk < 16; kk++)
#pragma unroll
            for (int i = 0; i < 4; i++)
#pragma unroll
                for (int j = 0; j < 4; j++)
                    acc[i][j] += Xs[kk][ty * 4 + i] * Ws[kk][tx * 4 + j];
        __syncthreads();
    }
    const float s = *sp;
#pragma unroll
    for (int i = 0; i < 4; i++)
#pragma unroll
        for (int j = 0; j < 4; j++)
            Y[(size_t)(m0 + ty * 4 + i) * N_DIM + n0 + tx * 4 + j] = acc[i][j] * s;
}

extern "C" void kernel_launch(void* const* d_in, const int* in_sizes, int n_in,
                              void* d_out, int out_size, void* d_ws, size_t ws_size,
                              hipStream_t stream) {
    const float* X  = (const float*)d_in[0];
    const int*   W  = (const int*)d_in[1];     // int8-valued, materialized as int32
    const float* sp = (const float*)d_in[2];
    float* Y = (float*)d_out;

    const size_t xb = (size_t)M_DIM * K_DIM * sizeof(u16);   // 64 MB
    const size_t wb = (size_t)N_DIM * K_DIM * sizeof(u16);   // 32 MB

    if (ws_size >= xb + wb) {
        u16* Xb = (u16*)d_ws;
        u16* Wt = (u16*)((char*)d_ws + xb);
        const int n8 = M_DIM * K_DIM / 8;   // 4,194,304 chunks
        cvt_x_kernel<<<n8 / 256, 256, 0, stream>>>(X, Xb);
        cvt_w_kernel<<<dim3(N_DIM / 64, K_DIM / 64), 256, 0, stream>>>(W, Wt);
        gemm_bf16_kernel<<<dim3(N_DIM / 128, M_DIM / 128), 256, 0, stream>>>(Xb, Wt, sp, Y);
    } else {
        fb_gemm_kernel<<<dim3(N_DIM / 64, M_DIM / 64), 256, 0, stream>>>(X, W, sp, Y);
    }
}

// Round 4
// 548.558 us; speedup vs baseline: 1.0363x; 1.0363x over previous
//
#include <hip/hip_runtime.h>
#include <cstdint>

typedef unsigned short u16;
typedef __bf16 bf16x8 __attribute__((ext_vector_type(8)));
typedef float f32x4 __attribute__((ext_vector_type(4)));
typedef int   i32x4 __attribute__((ext_vector_type(4)));   // NT-load friendly
typedef u16   u16x4 __attribute__((ext_vector_type(4)));

#define M_DIM 8192   // B*S = 4*2048
#define N_DIM 4096   // UNITS
#define K_DIM 4096   // D

#define GLOBAL_AS(p) ((const __attribute__((address_space(1))) void*)(p))
#define LDS_AS(p)    ((__attribute__((address_space(3))) void*)(p))

// ---------- fp32 -> bf16 bits, round-to-nearest-even ----------
__device__ __forceinline__ u16 f2bf(float f) {
    union { float f; uint32_t u; } x; x.f = f;
    uint32_t u = x.u;
    uint32_t r = (u + 0x7fffu + ((u >> 16) & 1u)) >> 16;
    return (u16)r;
}

// ---------- fused prepass: one kernel, W-transpose blocks + X-convert blocks ----------
// blocks [0,4096):  W (K,N) int32 -> Wt (N,K) bf16, 64x64 tile each (NT loads)
// blocks [4096,6144): X fp32 -> bf16, 4096 float4-chunks each, fully coalesced
// Xb/Wt stores stay cached (consumed by the GEMM); X/W loads are non-temporal
// (read-once) to avoid polluting L2/L3.
__global__ __launch_bounds__(256) void prepass_kernel(const float* __restrict__ X,
                                                      const int* __restrict__ W,
                                                      u16* __restrict__ Xb,
                                                      u16* __restrict__ Wt) {
    const int bid = blockIdx.x;
    const int t   = threadIdx.x;
    if (bid < 4096) {
        __shared__ int tile[64][65];                  // +1 pad: conflict-free column reads
        const int n0 = (bid & 63) * 64;
        const int k0 = (bid >> 6) * 64;
#pragma unroll
        for (int i = 0; i < 4; i++) {
            int e = t + i * 256;                      // 1024 int4-chunks
            int r = e >> 4;                           // row 0..63
            int c = (e & 15) * 4;                     // col 0..60
            i32x4 v = __builtin_nontemporal_load(
                (const i32x4*)(W + (size_t)(k0 + r) * N_DIM + n0 + c));
            tile[r][c] = v.x; tile[r][c + 1] = v.y; tile[r][c + 2] = v.z; tile[r][c + 3] = v.w;
        }
        __syncthreads();
        {   // thread t: row n = t>>2, k-span (t&3)*16 .. +16  (two 16B stores, cached)
            int n = t >> 2, ks = (t & 3) * 16;
            __align__(16) u16 o[16];
#pragma unroll
            for (int i = 0; i < 16; i++)
                o[i] = f2bf((float)tile[ks + i][n]);
            u16* dst = Wt + (size_t)(n0 + n) * K_DIM + k0 + ks;
            *(uint4*)(dst)     = *(const uint4*)&o[0];
            *(uint4*)(dst + 8) = *(const uint4*)&o[8];
        }
    } else {
        // X convert: block covers 4096 float4 = 64 KB; 8 iters x 512 float4
        const size_t base = (size_t)(bid - 4096) * 4096;
        const f32x4*   x4 = (const f32x4*)X;
        u16x4*         o4 = (u16x4*)Xb;               // u16x4 index == float4 index
#pragma unroll
        for (int it = 0; it < 8; it++) {
            size_t ia = base + (size_t)it * 512 + t;  // lanes contiguous -> coalesced
            size_t ib = ia + 256;
            f32x4 a = __builtin_nontemporal_load(x4 + ia);
            f32x4 b = __builtin_nontemporal_load(x4 + ib);
            u16x4 oa, ob;
            oa.x = f2bf(a.x); oa.y = f2bf(a.y); oa.z = f2bf(a.z); oa.w = f2bf(a.w);
            ob.x = f2bf(b.x); ob.y = f2bf(b.y); ob.z = f2bf(b.z); ob.w = f2bf(b.w);
            o4[ia] = oa;                              // cached: gemm reads these next
            o4[ib] = ob;
        }
    }
}

// ---------- main GEMM: C[M,N] = (A[M,K]bf16 . Bt[N,K]bf16) * scale ----------
// m97 structure: 128x128 tile, BK=32, 256 threads (4 waves, 2x2 of 64x64),
// global_load_lds width=16 into unpadded LDS, 16x16x32 bf16 MFMA.
// C stores are NON-TEMPORAL: C is write-once, and letting it allocate in L2/L3
// evicted Xb/Wt (R2 counters: FETCH 315 MB vs 96 MB ideal).
__global__ __launch_bounds__(256) void gemm_bf16_kernel(const u16* __restrict__ A,
                                                        const u16* __restrict__ Bt,
                                                        const float* __restrict__ scale_p,
                                                        float* __restrict__ C) {
    __shared__ u16 As[128 * 32];   // [m][k], unpadded (global_load_lds constraint)
    __shared__ u16 Bs[128 * 32];   // [n][k]

    const int tid  = threadIdx.x;
    const int lane = tid & 63;
    const int wv   = tid >> 6;
    const int m0   = blockIdx.y * 128;
    const int n0   = blockIdx.x * 128;

    const int wm = (wv >> 1) * 64;         // wave's 64x64 sub-tile
    const int wn = (wv & 1) * 64;
    const int fr = lane & 15;              // fragment row (m or n)
    const int fk = (lane >> 4) * 8;        // fragment k offset

    // staging: 512 chunks of 16B per tile; thread t covers chunks t and t+256.
    // chunk c -> row c>>2, k-offset (c&3)*8. LDS dest = wave-uniform base + lane*16B.
    const int c0 = tid, c1 = tid + 256;
    const u16* ga0 = A  + (size_t)(m0 + (c0 >> 2)) * K_DIM + (c0 & 3) * 8;
    const u16* ga1 = A  + (size_t)(m0 + (c1 >> 2)) * K_DIM + (c1 & 3) * 8;
    const u16* gb0 = Bt + (size_t)(n0 + (c0 >> 2)) * K_DIM + (c0 & 3) * 8;
    const u16* gb1 = Bt + (size_t)(n0 + (c1 >> 2)) * K_DIM + (c1 & 3) * 8;
    u16* lA0 = As + wv * 512;          // bytes: wv*1024
    u16* lA1 = As + 2048 + wv * 512;   // bytes: 4096 + wv*1024
    u16* lB0 = Bs + wv * 512;
    u16* lB1 = Bs + 2048 + wv * 512;

    f32x4 acc[4][4] = {};

    for (int k0 = 0; k0 < K_DIM; k0 += 32) {
        __builtin_amdgcn_global_load_lds(GLOBAL_AS(ga0 + k0), LDS_AS(lA0), 16, 0, 0);
        __builtin_amdgcn_global_load_lds(GLOBAL_AS(ga1 + k0), LDS_AS(lA1), 16, 0, 0);
        __builtin_amdgcn_global_load_lds(GLOBAL_AS(gb0 + k0), LDS_AS(lB0), 16, 0, 0);
        __builtin_amdgcn_global_load_lds(GLOBAL_AS(gb1 + k0), LDS_AS(lB1), 16, 0, 0);
        __syncthreads();

        bf16x8 af[4], bfr[4];
#pragma unroll
        for (int i = 0; i < 4; i++)
            af[i] = *(const bf16x8*)(As + (wm + i * 16 + fr) * 32 + fk);
#pragma unroll
        for (int j = 0; j < 4; j++)
            bfr[j] = *(const bf16x8*)(Bs + (wn + j * 16 + fr) * 32 + fk);
#pragma unroll
        for (int i = 0; i < 4; i++)
#pragma unroll
            for (int j = 0; j < 4; j++)
                acc[i][j] = __builtin_amdgcn_mfma_f32_16x16x32_bf16(af[i], bfr[j], acc[i][j], 0, 0, 0);
        __syncthreads();
    }

    // epilogue: D layout col=lane&15, row=(lane>>4)*4+reg; NT stores (write-once)
    const float s = *scale_p;
    const int orow = m0 + wm + (lane >> 4) * 4;
    const int ocol = n0 + wn + (lane & 15);
#pragma unroll
    for (int i = 0; i < 4; i++)
#pragma unroll
        for (int j = 0; j < 4; j++) {
            float* cp = C + (size_t)(orow + i * 16) * N_DIM + ocol + j * 16;
#pragma unroll
            for (int r = 0; r < 4; r++)
                __builtin_nontemporal_store(acc[i][j][r] * s, cp + (size_t)r * N_DIM);
        }
}

// ---------- fallback fp32 GEMM (only if ws too small; correctness net) ----------
__global__ __launch_bounds__(256) void fb_gemm_kernel(const float* __restrict__ X,
                                                      const int* __restrict__ W,
                                                      const float* __restrict__ sp,
                                                      float* __restrict__ Y) {
    __shared__ float Xs[16][64];
    __shared__ float Ws[16][64];
    const int t = threadIdx.x;
    const int tx = t & 15, ty = t >> 4;
    const int m0 = blockIdx.y * 64, n0 = blockIdx.x * 64;
    float acc[4][4] = {};
    for (int k0 = 0; k0 < K_DIM; k0 += 16) {
#pragma unroll
        for (int i = 0; i < 4; i++) {
            int e = t + i * 256;
            int r = e >> 4, c = e & 15;                 // 64 rows x 16 k
            Xs[c][r] = X[(size_t)(m0 + r) * K_DIM + k0 + c];
            int rw = e >> 6, cw = e & 63;               // 16 k x 64 n
            Ws[rw][cw] = (float)W[(size_t)(k0 + rw) * N_DIM + n0 + cw];
        }
        __syncthreads();
#pragma unroll
        for (int kk = 0; kk < 16; kk++)
#pragma unroll
            for (int i = 0; i < 4; i++)
#pragma unroll
                for (int j = 0; j < 4; j++)
                    acc[i][j] += Xs[kk][ty * 4 + i] * Ws[kk][tx * 4 + j];
        __syncthreads();
    }
    const float s = *sp;
#pragma unroll
    for (int i = 0; i < 4; i++)
#pragma unroll
        for (int j = 0; j < 4; j++)
            Y[(size_t)(m0 + ty * 4 + i) * N_DIM + n0 + tx * 4 + j] = acc[i][j] * s;
}

extern "C" void kernel_launch(void* const* d_in, const int* in_sizes, int n_in,
                              void* d_out, int out_size, void* d_ws, size_t ws_size,
                              hipStream_t stream) {
    const float* X  = (const float*)d_in[0];
    const int*   W  = (const int*)d_in[1];     // int8-valued, materialized as int32
    const float* sp = (const float*)d_in[2];
    float* Y = (float*)d_out;

    const size_t xb = (size_t)M_DIM * K_DIM * sizeof(u16);   // 64 MB
    const size_t wb = (size_t)N_DIM * K_DIM * sizeof(u16);   // 32 MB

    if (ws_size >= xb + wb) {
        u16* Xb = (u16*)d_ws;
        u16* Wt = (u16*)((char*)d_ws + xb);
        // 4096 W-tile blocks + 2048 X-convert blocks, one fused dispatch
        prepass_kernel<<<6144, 256, 0, stream>>>(X, W, Xb, Wt);
        gemm_bf16_kernel<<<dim3(N_DIM / 128, M_DIM / 128), 256, 0, stream>>>(Xb, Wt, sp, Y);
    } else {
        fb_gemm_kernel<<<dim3(N_DIM / 64, M_DIM / 64), 256, 0, stream>>>(X, W, sp, Y);
    }
}